// Round 1
// baseline (698.806 us; speedup 1.0000x reference)
//
#include <hip/hip_runtime.h>
#include <hip/hip_bf16.h>
#include <math.h>

// MambaRSSM forward, MI355X gfx950.
// Round 10 -> 11: GEMMs were tile-overhead-bound (MfmaUtil 7.5%, conflicts 0,
// HBM 8.8%): 64x64 tile = 4 MFMA per K-step vs 4 ds_read + 2 barriers.
// Port gemm_t to the m97 128x128/BK=32 structure: 4 waves x (4x4 16x16 frags),
// 16 MFMA / 8 ds_read_b128 / 4 gld16 per K-step; same XOR bank swizzle
// (structure [row][4x16B chunks] unchanged; (row>>1)&3 == (fm>>1)&3 since
// wm,wn in {0,64}). dtbc GEMM (N=1088) pads to 9 N-tiles with B-row clamp;
// cols >= 1088 are discarded by the epilogue as before.
// Shapes: B=8 T=512 ACT=32 EMB=DET=HID=1024 NST=16 STO=CLS=32.
// Row index: r = t*8 + b ((T,B) order).

typedef __bf16 bf16_t;
typedef __bf16 bf16x8 __attribute__((ext_vector_type(8)));
typedef float f32x4 __attribute__((ext_vector_type(4)));

#define B_   8
#define T_   512
#define R_   4096
#define HID_ 1024
#define NC_  32   // scan chunks
#define CL_  16   // steps per chunk

static __device__ __forceinline__ float bf2f(bf16_t x) { return (float)x; }
static __device__ __forceinline__ bf16_t f2bf(float x) { return (bf16_t)x; }
static __device__ __forceinline__ float ldany(const void* p, size_t i, bool isb) {
  return isb ? bf2f(((const bf16_t*)p)[i]) : ((const float*)p)[i];
}

typedef __attribute__((address_space(3))) unsigned int lds_u32;
typedef const __attribute__((address_space(1))) unsigned int glb_u32;
static __device__ __forceinline__ void gld16(const bf16_t* g, bf16_t* l) {
  __builtin_amdgcn_global_load_lds((glb_u32*)g, (lds_u32*)l, 16, 0, 0);
}

// ---------------- dtype detect: Dp is all-ones -----------------------------
__global__ void detect_k(const unsigned int* __restrict__ dp_raw, int* __restrict__ flag) {
  if (threadIdx.x == 0) *flag = (dp_raw[0] == 0x3F803F80u) ? 1 : 0;  // 1 = bf16 inputs
}

// ---------------- batched convert of small tensors to f32 ------------------
struct CvtArgs {
  const void* src[17];
  float* dst[17];
  int n[17];
};
__global__ __launch_bounds__(256) void cvt_vecs(CvtArgs a, const int* __restrict__ flag) {
  const bool isb = (*flag != 0);
  int v = blockIdx.y;
  const void* s = a.src[v];
  float* d = a.dst[v];
  int n = a.n[v];
  for (int i = blockIdx.x * 256 + threadIdx.x; i < n; i += 8 * 256)
    d[i] = ldany(s, i, isb);
}

// ---------------- block-wide sum of (s, ss), blockDim == 256 ----------------
__device__ __forceinline__ void block_sum2(float& s, float& ss) {
#pragma unroll
  for (int off = 32; off > 0; off >>= 1) {
    s  += __shfl_down(s, off, 64);
    ss += __shfl_down(ss, off, 64);
  }
  __shared__ float red[8];
  int tid = threadIdx.x;
  int wave = tid >> 6, lane = tid & 63;
  if (lane == 0) { red[wave] = s; red[4 + wave] = ss; }
  __syncthreads();
  s  = red[0] + red[1] + red[2] + red[3];
  ss = red[4] + red[5] + red[6] + red[7];
}

// ---------------- batched weight transpose (K,N)->(N,K) bf16, one dispatch --
struct TrArgs {
  const void* src[8];
  bf16_t* dst[8];
  int K[8], N[8];
  int tile0[9];   // exclusive prefix over (K/32)*(N/32)
};
__global__ void tr_batch(TrArgs a, const int* __restrict__ flag) {
  __shared__ float tile[32][33];
  const bool isb = (*flag != 0);
  int bid = blockIdx.x;
  int m = 0;
#pragma unroll
  for (int q = 0; q < 7; ++q) if (bid >= a.tile0[q + 1]) m = q + 1;
  int local = bid - a.tile0[m];
  int K = a.K[m], N = a.N[m];
  int ntx = N >> 5;
  int n0 = (local % ntx) * 32, k0 = (local / ntx) * 32;
  const void* src = a.src[m];
  bf16_t* dst = a.dst[m];
  int tx = threadIdx.x, ty = threadIdx.y;
#pragma unroll
  for (int i = 0; i < 4; ++i) {
    size_t idx = (size_t)(k0 + ty + i * 8) * N + n0 + tx;
    tile[ty + i * 8][tx] = ldany(src, idx, isb);
  }
  __syncthreads();
#pragma unroll
  for (int i = 0; i < 4; ++i)
    dst[(size_t)(n0 + ty + i * 8) * K + k0 + tx] = f2bf(tile[tx][ty + i * 8]);
}

// ---------------- rows 1024..1087 of WTdtbc = [W_B^T; W_C^T; zeros] ---------
__global__ __launch_bounds__(256) void bc_build(const void* __restrict__ W_B,
                                                const void* __restrict__ W_C,
                                                bf16_t* __restrict__ WTdtbc,
                                                const int* __restrict__ flag) {
  const bool isb = (*flag != 0);
  int idx = blockIdx.x * 256 + threadIdx.x;   // 65536 = 64 rows x 1024 cols
  int r = idx >> 10, k = idx & 1023;
  float v = 0.f;
  if (r < 16)      v = ldany(W_B, k * 16 + r, isb);
  else if (r < 32) v = ldany(W_C, k * 16 + (r - 16), isb);
  WTdtbc[(size_t)(1024 + r) * 1024 + k] = f2bf(v);
}

// ---------------- embeds (B,T,E) -> (T,B,E) bf16, dtype-aware ---------------
__global__ __launch_bounds__(256) void reorder_emb(const void* __restrict__ emb,
                                                   bf16_t* __restrict__ embT,
                                                   const int* __restrict__ flag) {
  const bool isb = (*flag != 0);
  int r = blockIdx.x, tid = threadIdx.x;
  int t = r >> 3, b = r & 7;
  size_t base = (size_t)(b * T_ + t) * 1024;
#pragma unroll
  for (int i = 0; i < 4; ++i) {
    int c = i * 256 + tid;
    embT[(size_t)r * 1024 + c] = f2bf(ldany(emb, base + c, isb));
  }
}

// ---------------- actions (B,T,32) -> (T,B,32) bf16 -------------------------
__global__ __launch_bounds__(256) void reorder_act(const void* __restrict__ act,
                                                   bf16_t* __restrict__ actA,
                                                   const int* __restrict__ flag) {
  const bool isb = (*flag != 0);
  int i = blockIdx.x * 256 + threadIdx.x;   // 131072
  int r = i >> 5, k = i & 31;
  int t = r >> 3, b = r & 7;
  actA[(size_t)r * 32 + k] = f2bf(ldany(act, (size_t)(b * T_ + t) * 32 + k, isb));
}

// ---------------- 128x128 MFMA GEMM, A(M,K) x Bt(N,K), swizzled LDS ---------
enum { EPI_ADD_BF16 = 0, EPI_XZ = 1, EPI_BIAS_F32 = 3, EPI_PRIOR = 4, EPI_DTBC = 6 };

struct GemmArgs {
  const bf16_t* A;     // M x K row-major
  const bf16_t* Bt;    // N x K row-major (pre-transposed weight)
  int K;               // lda = ldb = K
  int N;               // output leading dim (for EPI addressing)
  int bnN;             // number of 128-wide N tiles
  int Nrows;           // valid rows in Bt (clamp for padded last N tile)
  const float* bias;   // length >= min(N,1024) (canonical f32)
  const bf16_t* addh;  // EPI_ADD_BF16: bf16 addend, M x N
  float* outf0;        // f32 out (or dt for DTBC -> F1)
  float* outf1;        // EPI_DTBC: Bp
  float* outf2;        // EPI_DTBC: Cp
  bf16_t* outh0;
  bf16_t* outh1;
  void* outv;          // EPI_PRIOR: d_out base (dtype per flag)
  const int* flag;
};

// 1-D grid; tiles mapped so each XCD (bid&7) owns a contiguous bm band.
// LDS layout XOR-swizzled: chunk c=(row*4+blk) holds global col-block
// blk^((row>>1)&3); spreads each 16-lane ds_read_b128 phase over all banks.
// m97 structure: 128x128 tile, BK=32, 4 waves each computing a 64x64 subtile
// (4x4 of 16x16x32 MFMA) -> 16 MFMA per wave per K-step vs 8 ds_read_b128.
template <int EPI>
__global__ __launch_bounds__(256) void gemm_t(GemmArgs g) {
  __shared__ __align__(16) bf16_t As[128 * 32];   // 8 KB
  __shared__ __align__(16) bf16_t Bs[128 * 32];   // 8 KB
  const int tid = threadIdx.x;
  const int wave = tid >> 6, lane = tid & 63;
  const int K = g.K;

  const int per = gridDim.x >> 3;
  const int idx = (blockIdx.x & 7) * per + (blockIdx.x >> 3);
  const int bm = idx / g.bnN, bn = idx % g.bnN;

  f32x4 acc[4][4] = {};

  const int srow = tid >> 2;                        // 0..63
  const int sblk = (tid & 3) ^ ((srow >> 1) & 3);   // staging swizzle
  const bf16_t* Ap0 = g.A + (size_t)(bm * 128 + srow) * K + sblk * 8;
  const bf16_t* Ap1 = Ap0 + (size_t)64 * K;
  int br0 = bn * 128 + srow;
  int br1 = br0 + 64;
  if (br1 >= g.Nrows) br1 = 0;    // padded tile rows: garbage, epi-discarded
  if (br0 >= g.Nrows) br0 = 0;
  const bf16_t* Bp0 = g.Bt + (size_t)br0 * K + sblk * 8;
  const bf16_t* Bp1 = g.Bt + (size_t)br1 * K + sblk * 8;
  bf16_t* AsW0 = &As[tid * 8];
  bf16_t* AsW1 = &As[(tid + 256) * 8];
  bf16_t* BsW0 = &Bs[tid * 8];
  bf16_t* BsW1 = &Bs[(tid + 256) * 8];

  const int wm = (wave >> 1) * 64, wn = (wave & 1) * 64;
  const int fm = lane & 15;
  const int swz = (lane >> 4) ^ ((fm >> 1) & 3);    // read-side swizzle

  for (int k0 = 0; k0 < K; k0 += 32) {
    gld16(Ap0 + k0, AsW0);
    gld16(Ap1 + k0, AsW1);
    gld16(Bp0 + k0, BsW0);
    gld16(Bp1 + k0, BsW1);
    __syncthreads();
    bf16x8 af[4], bfr[4];
#pragma unroll
    for (int i = 0; i < 4; ++i)
      af[i] = *(const bf16x8*)&As[((wm + i * 16 + fm) * 4 + swz) * 8];
#pragma unroll
    for (int j = 0; j < 4; ++j)
      bfr[j] = *(const bf16x8*)&Bs[((wn + j * 16 + fm) * 4 + swz) * 8];
#pragma unroll
    for (int i = 0; i < 4; ++i)
#pragma unroll
      for (int j = 0; j < 4; ++j)
        acc[i][j] = __builtin_amdgcn_mfma_f32_16x16x32_bf16(af[i], bfr[j], acc[i][j], 0, 0, 0);
    __syncthreads();
  }

  const bool out_bf = (EPI == EPI_PRIOR) ? (*g.flag != 0) : false;
  const int em = (lane >> 4) * 4, en = lane & 15;
#pragma unroll
  for (int i = 0; i < 4; ++i) {
#pragma unroll
    for (int j = 0; j < 4; ++j) {
#pragma unroll
      for (int v = 0; v < 4; ++v) {
        int row = bm * 128 + wm + i * 16 + em + v;
        int col = bn * 128 + wn + j * 16 + en;
        float x = acc[i][j][v];
        if constexpr (EPI == EPI_ADD_BF16) {
          size_t o = (size_t)row * g.N + col;
          g.outh0[o] = f2bf(x + bf2f(g.addh[o]));
        } else if constexpr (EPI == EPI_XZ) {
          float val = x + g.bias[col];
          if (col < 1024) g.outh0[(size_t)row * 1024 + col] = f2bf(val);
          else            g.outh1[(size_t)row * 1024 + (col - 1024)] = f2bf(val);
        } else if constexpr (EPI == EPI_BIAS_F32) {
          g.outf0[(size_t)row * g.N + col] = x + g.bias[col];
        } else if constexpr (EPI == EPI_DTBC) {
          if (col < 1024) {
            float val = x + g.bias[col];
            float sp = (val > 20.f) ? val : log1pf(__expf(val));
            g.outf0[(size_t)row * 1024 + col] = sp;          // dt
          } else if (col < 1040) {
            g.outf1[(size_t)row * 16 + (col - 1024)] = x;     // Bp
          } else if (col < 1056) {
            g.outf2[(size_t)row * 16 + (col - 1040)] = x;     // Cp
          }
        } else {  // EPI_PRIOR: d_out[:, 1024:2048], dtype per flag
          float val = x + g.bias[col];
          size_t o = (size_t)row * 3072 + 1024 + col;
          if (out_bf) ((bf16_t*)g.outv)[o] = f2bf(val);
          else        ((float*)g.outv)[o]  = val;
        }
      }
    }
  }
}

// ---------------- chunked scan, phase 1 (xs is bf16 now) --------------------
__global__ __launch_bounds__(256) void scan_p1(const float* __restrict__ dt,
                                               const bf16_t* __restrict__ xsh,
                                               const float* __restrict__ Bp,
                                               const float* __restrict__ A_log,
                                               float* __restrict__ Gp,
                                               float* __restrict__ Hl) {
  int idx = blockIdx.x * 256 + threadIdx.x;
  int d = idx & 1023;
  int cb = idx >> 10;
  int b = cb & 7, c = cb >> 3;
  float Ad[16];
#pragma unroll
  for (int n = 0; n < 16; ++n) Ad[n] = -__expf(A_log[d * 16 + n]);
  float h[16] = {};
  float dts = 0.f;
  int r0 = c * CL_ * 8 + b;
  for (int tl = 0; tl < CL_; ++tl) {
    int r = r0 + tl * 8;
    size_t off = (size_t)r * 1024 + d;
    float dtv = dt[off], xv = bf2f(xsh[off]);
    float dtx = dtv * xv;
    dts += dtv;
    const float4* Bp4 = (const float4*)(Bp + r * 16);
    float4 b4[4] = {Bp4[0], Bp4[1], Bp4[2], Bp4[3]};
    const float* bv = (const float*)b4;
#pragma unroll
    for (int n = 0; n < 16; ++n) {
      float gg = __expf(dtv * Ad[n]);
      h[n] = gg * h[n] + dtx * bv[n];
    }
  }
  float* gp = Gp + (size_t)idx * 16;
  float* hl = Hl + (size_t)idx * 16;
#pragma unroll
  for (int q = 0; q < 4; ++q) {
    float4 gq, hq;
    gq.x = __expf(dts * Ad[q * 4 + 0]); gq.y = __expf(dts * Ad[q * 4 + 1]);
    gq.z = __expf(dts * Ad[q * 4 + 2]); gq.w = __expf(dts * Ad[q * 4 + 3]);
    hq.x = h[q * 4 + 0]; hq.y = h[q * 4 + 1]; hq.z = h[q * 4 + 2]; hq.w = h[q * 4 + 3];
    ((float4*)gp)[q] = gq;
    ((float4*)hl)[q] = hq;
  }
}

// ---------------- phase 2: inter-chunk carry scan; Cin overwrites Gp --------
__global__ __launch_bounds__(256) void scan_p2(float* __restrict__ GpCin,
                                               const float* __restrict__ Hl) {
  int j = blockIdx.x * 256 + threadIdx.x;
  float carry = 0.f;
#pragma unroll
  for (int c = 0; c < NC_; ++c) {
    size_t o = (size_t)c * 131072 + j;
    float gv = GpCin[o], hl = Hl[o];
    GpCin[o] = carry;
    carry = gv * carry + hl;
  }
}

// ---------------- phase 3: replay chunks from carry-in, emit gated y --------
__global__ __launch_bounds__(256) void scan_p3(const float* __restrict__ dt,
                                               const bf16_t* __restrict__ xsh,
                                               const bf16_t* __restrict__ xg,
                                               const float* __restrict__ Bp,
                                               const float* __restrict__ Cp,
                                               const float* __restrict__ A_log,
                                               const float* __restrict__ Dp,
                                               const float* __restrict__ Cin,
                                               float* __restrict__ y) {
  int idx = blockIdx.x * 256 + threadIdx.x;
  int d = idx & 1023;
  int cb = idx >> 10;
  int b = cb & 7, c = cb >> 3;
  float Ad[16];
#pragma unroll
  for (int n = 0; n < 16; ++n) Ad[n] = -__expf(A_log[d * 16 + n]);
  float Dd = Dp[d];
  float h[16];
  const float4* Ci4 = (const float4*)(Cin + (size_t)idx * 16);
#pragma unroll
  for (int q = 0; q < 4; ++q) {
    float4 cq = Ci4[q];
    h[q * 4 + 0] = cq.x; h[q * 4 + 1] = cq.y; h[q * 4 + 2] = cq.z; h[q * 4 + 3] = cq.w;
  }
  int r0 = c * CL_ * 8 + b;
  for (int tl = 0; tl < CL_; ++tl) {
    int r = r0 + tl * 8;
    size_t off = (size_t)r * 1024 + d;
    float dtv = dt[off], xv = bf2f(xsh[off]), gv = bf2f(xg[off]);
    float dtx = dtv * xv;
    const float4* Bp4 = (const float4*)(Bp + r * 16);
    const float4* Cp4 = (const float4*)(Cp + r * 16);
    float4 b4[4] = {Bp4[0], Bp4[1], Bp4[2], Bp4[3]};
    float4 c4[4] = {Cp4[0], Cp4[1], Cp4[2], Cp4[3]};
    const float* bv = (const float*)b4;
    const float* cv = (const float*)c4;
    float yv = 0.f;
#pragma unroll
    for (int n = 0; n < 16; ++n) {
      float gg = __expf(dtv * Ad[n]);
      h[n] = gg * h[n] + dtx * bv[n];
      yv += h[n] * cv[n];
    }
    yv += Dd * xv;
    float sg = gv / (1.f + __expf(-gv));   // silu(x_gate)
    y[off] = yv * sg;
  }
}

// ---------------- row LN; MODE 0: deter triple-write (+post_in assemble),
//                  MODE 1: +silu -> bf16 -------------------------------------
template <int MODE>
__global__ __launch_bounds__(256) void ln_k(const float* __restrict__ in,
                                            const float* __restrict__ gw,
                                            const float* __restrict__ bw,
                                            bf16_t* __restrict__ out0,
                                            void* __restrict__ out1,
                                            const bf16_t* __restrict__ embT,
                                            bf16_t* __restrict__ post_in,
                                            const int* __restrict__ flag) {
  const bool out_bf = (MODE == 0) ? (*flag != 0) : false;
  int r = blockIdx.x, tid = threadIdx.x;
  float v[4];
  float s = 0.f, ss = 0.f;
#pragma unroll
  for (int i = 0; i < 4; ++i) {
    v[i] = in[(size_t)r * 1024 + i * 256 + tid];
    s += v[i]; ss += v[i] * v[i];
  }
  block_sum2(s, ss);   // barrier: all row reads resolved before any write below
  float mean = s * (1.f / 1024.f);
  float var  = ss * (1.f / 1024.f) - mean * mean;
  float rstd = rsqrtf(var + 1e-5f);
#pragma unroll
  for (int i = 0; i < 4; ++i) {
    int c = i * 256 + tid;
    float yv = (v[i] - mean) * rstd * gw[c] + bw[c];
    if constexpr (MODE == 1) yv = yv / (1.f + __expf(-yv));
    out0[(size_t)r * 1024 + c] = f2bf(yv);
    if constexpr (MODE == 0) {
      size_t o = (size_t)r * 3072 + c;
      if (out_bf) ((bf16_t*)out1)[o] = f2bf(yv);
      else        ((float*)out1)[o]  = yv;
      post_in[(size_t)r * 2048 + c] = f2bf(yv);
      post_in[(size_t)r * 2048 + 1024 + c] = embT[(size_t)r * 1024 + c];
    }
  }
}

// ---------------- softmax over 32 classes + unimix + log -------------------
__global__ __launch_bounds__(256) void softmax_k(const float* __restrict__ logits,
                                                 void* __restrict__ out,
                                                 const int* __restrict__ flag) {
  const bool out_bf = (*flag != 0);
  int idx = blockIdx.x * 256 + threadIdx.x;
  int r = idx >> 5, grp = idx & 31;
  const float* p = logits + (size_t)r * 1024 + grp * 32;
  float x[32];
  float m = -1e30f;
#pragma unroll
  for (int j = 0; j < 32; ++j) { x[j] = p[j]; m = fmaxf(m, x[j]); }
  float sum = 0.f;
#pragma unroll
  for (int j = 0; j < 32; ++j) { x[j] = __expf(x[j] - m); sum += x[j]; }
  float inv = 0.99f / sum;
  size_t base = (size_t)r * 3072 + 2048 + grp * 32;
#pragma unroll
  for (int j = 0; j < 32; ++j) {
    float val = logf(x[j] * inv + (0.01f / 32.f) + 1e-8f);
    if (out_bf) ((bf16_t*)out)[base + j] = f2bf(val);
    else        ((float*)out)[base + j]  = val;
  }
}

// ===========================================================================
extern "C" void kernel_launch(void* const* d_in, const int* in_sizes, int n_in,
                              void* d_out, int out_size, void* d_ws, size_t ws_size,
                              hipStream_t stream) {
  (void)in_sizes; (void)n_in; (void)out_size; (void)ws_size;
  const void* actions = d_in[0];
  const void* embeds  = d_in[1];
  const void* W_pre   = d_in[2];
  const void* b_pre   = d_in[3];
  const void* g_pre   = d_in[4];
  const void* bb_pre  = d_in[5];
  const void* W_emb   = d_in[6];
  const void* W_in    = d_in[7];
  const void* b_in    = d_in[8];
  const void* W_dt    = d_in[9];
  const void* b_dt    = d_in[10];
  const void* W_B     = d_in[11];
  const void* W_C     = d_in[12];
  const void* A_log   = d_in[13];
  const void* Dp      = d_in[14];
  const void* g_out   = d_in[15];
  const void* b_out   = d_in[16];
  const void* W_pr1   = d_in[17];
  const void* b_pr1   = d_in[18];
  const void* g_pr    = d_in[19];
  const void* bb_pr   = d_in[20];
  const void* W_pr2   = d_in[21];
  const void* b_pr2   = d_in[22];
  const void* W_po1   = d_in[23];
  const void* b_po1   = d_in[24];
  const void* g_po    = d_in[25];
  const void* bb_po   = d_in[26];
  const void* W_po2   = d_in[27];
  const void* b_po2   = d_in[28];

  // ---- workspace layout (offsets in KB; ~99.2 MB total). Aliases:
  //   Hl @ F5; Gp @ F2 (free until z2); B9 (x_ssm bf16) stays LIVE thru scan.
  char* ws = (char*)d_ws;
  const size_t KB = 1024;
  bf16_t* WTemb  = (bf16_t*)(ws + 0 * KB);       // 1024x1024 (2 MB)
  bf16_t* WTin   = (bf16_t*)(ws + 2048 * KB);    // 2048x1024 (4 MB)
  bf16_t* WTdtbc = (bf16_t*)(ws + 6144 * KB);    // 1088x1024 (2.125 MB)
  bf16_t* WTpr1  = (bf16_t*)(ws + 8320 * KB);
  bf16_t* WTpr2  = (bf16_t*)(ws + 10368 * KB);
  bf16_t* WTpo1  = (bf16_t*)(ws + 12416 * KB);   // 1024x2048 (4 MB)
  bf16_t* WTpo2  = (bf16_t*)(ws + 16512 * KB);
  bf16_t* embT   = (bf16_t*)(ws + 18560 * KB);   // 4096x1024 bf16 (8 MB)
  float*  F1     = (float*)(ws + 26752 * KB);    // pre_raw -> dt -> z1 -> logits
  float*  F2     = (float*)(ws + 43136 * KB);    // (Gp during scan) -> z2
  float*  F5     = (float*)(ws + 59520 * KB);    // (Hl) -> y -> post_in(bf16)
  bf16_t* B8     = (bf16_t*)(ws + 75904 * KB);   // act_h -> x -> h1 -> h2
  bf16_t* B9     = (bf16_t*)(ws + 84096 * KB);   // x_ssm bf16 (live thru scan) -> deter
  bf16_t* G8     = (bf16_t*)(ws + 92288 * KB);   // x_gate bf16
  float*  BpB    = (float*)(ws + 100480 * KB);   // 4096x16
  float*  CpB    = (float*)(ws + 100736 * KB);
  float*  Hl     = (float*)(ws + 59520 * KB);    // 16 MB (aliases F5)
  float*  Gp     = (float*)(ws + 43136 * KB);    // 16 MB (aliases F2)
  char* cb = ws + 100992 * KB;
  int*   flag    = (int*)(cb);                cb += 256;
  float* Alog_f  = (float*)(cb);              cb += 16384 * 4;
  float* Dp_f    = (float*)(cb);              cb += 1024 * 4;
  float* bpre_f  = (float*)(cb);              cb += 1024 * 4;
  float* gpre_f  = (float*)(cb);              cb += 1024 * 4;
  float* bbpre_f = (float*)(cb);              cb += 1024 * 4;
  float* bin_f   = (float*)(cb);              cb += 2048 * 4;
  float* bdt_f   = (float*)(cb);              cb += 1024 * 4;
  float* gout_f  = (float*)(cb);              cb += 1024 * 4;
  float* bout_f  = (float*)(cb);              cb += 1024 * 4;
  float* bpr1_f  = (float*)(cb);              cb += 1024 * 4;
  float* gpr_f   = (float*)(cb);              cb += 1024 * 4;
  float* bbpr_f  = (float*)(cb);              cb += 1024 * 4;
  float* bpr2_f  = (float*)(cb);              cb += 1024 * 4;
  float* bpo1_f  = (float*)(cb);              cb += 1024 * 4;
  float* gpo_f   = (float*)(cb);              cb += 1024 * 4;
  float* bbpo_f  = (float*)(cb);              cb += 1024 * 4;
  float* bpo2_f  = (float*)(cb);              cb += 1024 * 4;
  bf16_t* actA   = (bf16_t*)(cb);             cb += 4096 * 32 * 2;    // 256 KB
  bf16_t* WTpre  = (bf16_t*)(cb);             cb += 1024 * 32 * 2;    // 64 KB

  detect_k<<<1, 64, 0, stream>>>((const unsigned int*)Dp, flag);

  CvtArgs ca{};
  const void* srcs[17] = {A_log, Dp, b_pre, g_pre, bb_pre, b_in, b_dt,
                          g_out, b_out, b_pr1, g_pr, bb_pr, b_pr2,
                          b_po1, g_po, bb_po, b_po2};
  float* dsts[17] = {Alog_f, Dp_f, bpre_f, gpre_f, bbpre_f, bin_f, bdt_f,
                     gout_f, bout_f, bpr1_f, gpr_f, bbpr_f, bpr2_f,
                     bpo1_f, gpo_f, bbpo_f, bpo2_f};
  int ns[17] = {16384, 1024, 1024, 1024, 1024, 2048, 1024,
                1024, 1024, 1024, 1024, 1024, 1024,
                1024, 1024, 1024, 1024};
  for (int i = 0; i < 17; ++i) { ca.src[i] = srcs[i]; ca.dst[i] = dsts[i]; ca.n[i] = ns[i]; }
  cvt_vecs<<<dim3(8, 17), 256, 0, stream>>>(ca, flag);

  {  // all 8 weight transposes in one dispatch; W_dt^T lands in WTdtbc rows 0-1023
    TrArgs ta{};
    const void* tsrc[8] = {W_emb, W_in, W_dt, W_pr1, W_pr2, W_po1, W_po2, W_pre};
    bf16_t* tdst[8] = {WTemb, WTin, WTdtbc, WTpr1, WTpr2, WTpo1, WTpo2, WTpre};
    int tK[8] = {1024, 1024, 1024, 1024, 1024, 2048, 1024, 32};
    int tN[8] = {1024, 2048, 1024, 1024, 1024, 1024, 1024, 1024};
    int off = 0;
    for (int i = 0; i < 8; ++i) {
      ta.src[i] = tsrc[i]; ta.dst[i] = tdst[i]; ta.K[i] = tK[i]; ta.N[i] = tN[i];
      ta.tile0[i] = off; off += (tK[i] >> 5) * (tN[i] >> 5);
    }
    ta.tile0[8] = off;
    tr_batch<<<off, dim3(32, 8), 0, stream>>>(ta, flag);
  }
  bc_build<<<256, 256, 0, stream>>>(W_B, W_C, WTdtbc, flag);

  reorder_emb<<<R_, 256, 0, stream>>>(embeds, embT, flag);
  reorder_act<<<512, 256, 0, stream>>>(actions, actA, flag);

  {  // pre_raw = actions @ W_pre + b_pre -> f32 (F5); K=32 single MFMA step
    GemmArgs a{}; a.A = actA; a.Bt = WTpre; a.K = 32; a.N = 1024; a.bnN = 8;
    a.Nrows = 1024; a.bias = bpre_f; a.outf0 = F5;
    gemm_t<EPI_BIAS_F32><<<256, 256, 0, stream>>>(a);
  }
  // act_h = silu(LN(pre_raw)) -> bf16 (B8)
  ln_k<1><<<R_, 256, 0, stream>>>(F5, gpre_f, bbpre_f, B8, nullptr,
                                  nullptr, nullptr, flag);
  {  // x = embT @ W_emb + act_h -> bf16 (G8); addend B8 read-only here
    GemmArgs a{}; a.A = embT; a.Bt = WTemb; a.K = 1024; a.N = 1024; a.bnN = 8;
    a.Nrows = 1024; a.addh = B8; a.outh0 = G8;
    gemm_t<EPI_ADD_BF16><<<256, 256, 0, stream>>>(a);
  }
  {  // xz = x @ W_in + b_in -> x_ssm (bf16 B9), x_gate (bf16 B8)
    GemmArgs a{}; a.A = G8; a.Bt = WTin; a.K = 1024; a.N = 2048; a.bnN = 16;
    a.Nrows = 2048; a.bias = bin_f; a.outh0 = B9; a.outh1 = B8;
    gemm_t<EPI_XZ><<<512, 256, 0, stream>>>(a);
  }
  {  // dt=softplus(x_ssm@W_dt+b_dt)->F1; Bp/Cp = x_ssm@[W_B|W_C] (fused)
     // N padded to 9 tiles of 128; Bt rows clamped at Nrows=1088.
    GemmArgs a{}; a.A = B9; a.Bt = WTdtbc; a.K = 1024; a.N = 1152; a.bnN = 9;
    a.Nrows = 1088; a.bias = bdt_f; a.outf0 = F1; a.outf1 = BpB; a.outf2 = CpB;
    gemm_t<EPI_DTBC><<<288, 256, 0, stream>>>(a);
  }
  // chunked selective scan: 32 chunks x 16 steps (xs = B9 bf16, xg = B8)
  scan_p1<<<1024, 256, 0, stream>>>(F1, B9, BpB, Alog_f, Gp, Hl);
  scan_p2<<<512, 256, 0, stream>>>(Gp, Hl);
  scan_p3<<<1024, 256, 0, stream>>>(F1, B9, B8, BpB, CpB, Alog_f, Dp_f, Gp, F5);
  // deter = LN(y) -> bf16 (B9), d_out[:, 0:1024], and fused post_in (F5)
  ln_k<0><<<R_, 256, 0, stream>>>(F5, gout_f, bout_f, B9, d_out,
                                  embT, (bf16_t*)F5, flag);
  {  // z1 = deter @ W_pr1 + b_pr1 -> f32 (F1)
    GemmArgs a{}; a.A = B9; a.Bt = WTpr1; a.K = 1024; a.N = 1024; a.bnN = 8;
    a.Nrows = 1024; a.bias = bpr1_f; a.outf0 = F1;
    gemm_t<EPI_BIAS_F32><<<256, 256, 0, stream>>>(a);
  }
  ln_k<1><<<R_, 256, 0, stream>>>(F1, gpr_f, bbpr_f, B8, nullptr,
                                  nullptr, nullptr, flag);  // h1
  {  // prior = h1 @ W_pr2 + b_pr2 -> d_out[:, 1024:2048]
    GemmArgs a{}; a.A = B8; a.Bt = WTpr2; a.K = 1024; a.N = 1024; a.bnN = 8;
    a.Nrows = 1024; a.bias = bpr2_f; a.outv = d_out; a.flag = flag;
    gemm_t<EPI_PRIOR><<<256, 256, 0, stream>>>(a);
  }
  {  // z2 = post_in @ W_po1 + b_po1 -> f32 (F2)
    GemmArgs a{}; a.A = (bf16_t*)F5; a.Bt = WTpo1; a.K = 2048; a.N = 1024; a.bnN = 8;
    a.Nrows = 1024; a.bias = bpo1_f; a.outf0 = F2;
    gemm_t<EPI_BIAS_F32><<<256, 256, 0, stream>>>(a);
  }
  ln_k<1><<<R_, 256, 0, stream>>>(F2, gpo_f, bbpo_f, B8, nullptr,
                                  nullptr, nullptr, flag);  // h2
  {  // logits = h2 @ W_po2 + b_po2 -> f32 (F1)
    GemmArgs a{}; a.A = B8; a.Bt = WTpo2; a.K = 1024; a.N = 1024; a.bnN = 8;
    a.Nrows = 1024; a.bias = bpo2_f; a.outf0 = F1;
    gemm_t<EPI_BIAS_F32><<<256, 256, 0, stream>>>(a);
  }
  softmax_k<<<512, 256, 0, stream>>>(F1, d_out, flag);
}

// Round 2
// 509.534 us; speedup vs baseline: 1.3715x; 1.3715x over previous
//
#include <hip/hip_runtime.h>
#include <hip/hip_bf16.h>
#include <math.h>

// MambaRSSM forward, MI355X gfx950.
// Round 11 -> 12: 128x128 tile collapsed to 1 block/CU (grid 256) and the
// per-K-step vmcnt(0) barrier drain was fully exposed (MfmaUtil 2.6%,
// 10.5K cyc/K-step). These GEMMs are small (M=4096, N=1024-2048), so fix
// latency INSIDE the block: 128x64 tile (grid 512 = 2 blocks/CU), BK=32,
// double-buffered LDS, 2-phase schedule (issue next-tile global_load_lds
// BEFORE computing current tile; ONE barrier per K-step). dtbc N=1088 is
// exactly 17 x 64 -> no padding/clamp needed. Same XOR bank swizzle
// (wm in {0,64}, wn in {0,32} preserve (row>>1)&3 == (fm>>1)&3).
// Shapes: B=8 T=512 ACT=32 EMB=DET=HID=1024 NST=16 STO=CLS=32.
// Row index: r = t*8 + b ((T,B) order).

typedef __bf16 bf16_t;
typedef __bf16 bf16x8 __attribute__((ext_vector_type(8)));
typedef float f32x4 __attribute__((ext_vector_type(4)));

#define B_   8
#define T_   512
#define R_   4096
#define HID_ 1024
#define NC_  32   // scan chunks
#define CL_  16   // steps per chunk

static __device__ __forceinline__ float bf2f(bf16_t x) { return (float)x; }
static __device__ __forceinline__ bf16_t f2bf(float x) { return (bf16_t)x; }
static __device__ __forceinline__ float ldany(const void* p, size_t i, bool isb) {
  return isb ? bf2f(((const bf16_t*)p)[i]) : ((const float*)p)[i];
}

typedef __attribute__((address_space(3))) unsigned int lds_u32;
typedef const __attribute__((address_space(1))) unsigned int glb_u32;
static __device__ __forceinline__ void gld16(const bf16_t* g, bf16_t* l) {
  __builtin_amdgcn_global_load_lds((glb_u32*)g, (lds_u32*)l, 16, 0, 0);
}

// ---------------- dtype detect: Dp is all-ones -----------------------------
__global__ void detect_k(const unsigned int* __restrict__ dp_raw, int* __restrict__ flag) {
  if (threadIdx.x == 0) *flag = (dp_raw[0] == 0x3F803F80u) ? 1 : 0;  // 1 = bf16 inputs
}

// ---------------- batched convert of small tensors to f32 ------------------
struct CvtArgs {
  const void* src[17];
  float* dst[17];
  int n[17];
};
__global__ __launch_bounds__(256) void cvt_vecs(CvtArgs a, const int* __restrict__ flag) {
  const bool isb = (*flag != 0);
  int v = blockIdx.y;
  const void* s = a.src[v];
  float* d = a.dst[v];
  int n = a.n[v];
  for (int i = blockIdx.x * 256 + threadIdx.x; i < n; i += 8 * 256)
    d[i] = ldany(s, i, isb);
}

// ---------------- block-wide sum of (s, ss), blockDim == 256 ----------------
__device__ __forceinline__ void block_sum2(float& s, float& ss) {
#pragma unroll
  for (int off = 32; off > 0; off >>= 1) {
    s  += __shfl_down(s, off, 64);
    ss += __shfl_down(ss, off, 64);
  }
  __shared__ float red[8];
  int tid = threadIdx.x;
  int wave = tid >> 6, lane = tid & 63;
  if (lane == 0) { red[wave] = s; red[4 + wave] = ss; }
  __syncthreads();
  s  = red[0] + red[1] + red[2] + red[3];
  ss = red[4] + red[5] + red[6] + red[7];
}

// ---------------- batched weight transpose (K,N)->(N,K) bf16, one dispatch --
struct TrArgs {
  const void* src[8];
  bf16_t* dst[8];
  int K[8], N[8];
  int tile0[9];   // exclusive prefix over (K/32)*(N/32)
};
__global__ void tr_batch(TrArgs a, const int* __restrict__ flag) {
  __shared__ float tile[32][33];
  const bool isb = (*flag != 0);
  int bid = blockIdx.x;
  int m = 0;
#pragma unroll
  for (int q = 0; q < 7; ++q) if (bid >= a.tile0[q + 1]) m = q + 1;
  int local = bid - a.tile0[m];
  int K = a.K[m], N = a.N[m];
  int ntx = N >> 5;
  int n0 = (local % ntx) * 32, k0 = (local / ntx) * 32;
  const void* src = a.src[m];
  bf16_t* dst = a.dst[m];
  int tx = threadIdx.x, ty = threadIdx.y;
#pragma unroll
  for (int i = 0; i < 4; ++i) {
    size_t idx = (size_t)(k0 + ty + i * 8) * N + n0 + tx;
    tile[ty + i * 8][tx] = ldany(src, idx, isb);
  }
  __syncthreads();
#pragma unroll
  for (int i = 0; i < 4; ++i)
    dst[(size_t)(n0 + ty + i * 8) * K + k0 + tx] = f2bf(tile[tx][ty + i * 8]);
}

// ---------------- rows 1024..1087 of WTdtbc = [W_B^T; W_C^T; zeros] ---------
__global__ __launch_bounds__(256) void bc_build(const void* __restrict__ W_B,
                                                const void* __restrict__ W_C,
                                                bf16_t* __restrict__ WTdtbc,
                                                const int* __restrict__ flag) {
  const bool isb = (*flag != 0);
  int idx = blockIdx.x * 256 + threadIdx.x;   // 65536 = 64 rows x 1024 cols
  int r = idx >> 10, k = idx & 1023;
  float v = 0.f;
  if (r < 16)      v = ldany(W_B, k * 16 + r, isb);
  else if (r < 32) v = ldany(W_C, k * 16 + (r - 16), isb);
  WTdtbc[(size_t)(1024 + r) * 1024 + k] = f2bf(v);
}

// ---------------- embeds (B,T,E) -> (T,B,E) bf16, dtype-aware ---------------
__global__ __launch_bounds__(256) void reorder_emb(const void* __restrict__ emb,
                                                   bf16_t* __restrict__ embT,
                                                   const int* __restrict__ flag) {
  const bool isb = (*flag != 0);
  int r = blockIdx.x, tid = threadIdx.x;
  int t = r >> 3, b = r & 7;
  size_t base = (size_t)(b * T_ + t) * 1024;
#pragma unroll
  for (int i = 0; i < 4; ++i) {
    int c = i * 256 + tid;
    embT[(size_t)r * 1024 + c] = f2bf(ldany(emb, base + c, isb));
  }
}

// ---------------- actions (B,T,32) -> (T,B,32) bf16 -------------------------
__global__ __launch_bounds__(256) void reorder_act(const void* __restrict__ act,
                                                   bf16_t* __restrict__ actA,
                                                   const int* __restrict__ flag) {
  const bool isb = (*flag != 0);
  int i = blockIdx.x * 256 + threadIdx.x;   // 131072
  int r = i >> 5, k = i & 31;
  int t = r >> 3, b = r & 7;
  actA[(size_t)r * 32 + k] = f2bf(ldany(act, (size_t)(b * T_ + t) * 32 + k, isb));
}

// ---------------- 128x64 MFMA GEMM, A(M,K) x Bt(N,K), dbuf + 2-phase --------
enum { EPI_ADD_BF16 = 0, EPI_XZ = 1, EPI_BIAS_F32 = 3, EPI_PRIOR = 4, EPI_DTBC = 6 };

struct GemmArgs {
  const bf16_t* A;     // M x K row-major
  const bf16_t* Bt;    // N x K row-major (pre-transposed weight)
  int K;               // lda = ldb = K
  int N;               // output leading dim (for EPI addressing)
  int bnN;             // number of 64-wide N tiles
  const float* bias;   // length >= min(N,1024) (canonical f32)
  const bf16_t* addh;  // EPI_ADD_BF16: bf16 addend, M x N
  float* outf0;        // f32 out (or dt for DTBC -> F1)
  float* outf1;        // EPI_DTBC: Bp
  float* outf2;        // EPI_DTBC: Cp
  bf16_t* outh0;
  bf16_t* outh1;
  void* outv;          // EPI_PRIOR: d_out base (dtype per flag)
  const int* flag;
};

// 1-D grid; tiles mapped so each XCD (bid&7) owns a contiguous bm band.
// LDS layout XOR-swizzled: chunk slot c holds global col-block
// c^((row>>1)&3); spreads each 16-lane ds_read_b128 phase over all banks.
// 128x64 tile, BK=32, 4 waves each computing a 64x32 subtile (4x2 of
// 16x16x32 MFMA) -> 8 MFMA per wave per K-step vs 6 ds_read_b128.
// Double-buffered: next K-tile's global_load_lds issued BEFORE current
// compute; single __syncthreads per K-step (drains vmcnt+lgkm).
template <int EPI>
__global__ __launch_bounds__(256) void gemm_t(GemmArgs g) {
  __shared__ __align__(16) bf16_t As[2][128 * 32];   // 8 KB each
  __shared__ __align__(16) bf16_t Bs[2][64 * 32];    // 4 KB each
  const int tid = threadIdx.x;
  const int wave = tid >> 6, lane = tid & 63;
  const int K = g.K;

  const int per = gridDim.x >> 3;
  const int idx = (blockIdx.x & 7) * per + (blockIdx.x >> 3);
  const int bm = idx / g.bnN, bn = idx % g.bnN;

  f32x4 acc[4][2] = {};

  const int srow = tid >> 2;                        // 0..63
  const int sblk = (tid & 3) ^ ((srow >> 1) & 3);   // staging swizzle
  const bf16_t* Ap0 = g.A + (size_t)(bm * 128 + srow) * K + sblk * 8;
  const bf16_t* Ap1 = Ap0 + (size_t)64 * K;         // rows 64..127 (same swz: +64 keeps (row>>1)&3)
  const bf16_t* Bp  = g.Bt + (size_t)(bn * 64 + srow) * K + sblk * 8;

  const int wm = (wave >> 1) * 64, wn = (wave & 1) * 32;
  const int fm = lane & 15;
  const int swz = (lane >> 4) ^ ((fm >> 1) & 3);    // read-side swizzle

  const int nt = K >> 5;
  // prologue: stage tile 0 into buffer 0
  gld16(Ap0, &As[0][tid * 8]);
  gld16(Ap1, &As[0][(tid + 256) * 8]);
  gld16(Bp,  &Bs[0][tid * 8]);
  __syncthreads();   // vmcnt(0) drain: tile 0 resident

  int cur = 0;
  for (int t = 0; t < nt; ++t) {
    if (t + 1 < nt) {   // issue next-tile loads first; latency hides under compute
      int k0 = (t + 1) << 5;
      gld16(Ap0 + k0, &As[cur ^ 1][tid * 8]);
      gld16(Ap1 + k0, &As[cur ^ 1][(tid + 256) * 8]);
      gld16(Bp + k0,  &Bs[cur ^ 1][tid * 8]);
    }
    bf16x8 af[4], bfr[2];
#pragma unroll
    for (int i = 0; i < 4; ++i)
      af[i] = *(const bf16x8*)&As[cur][((wm + i * 16 + fm) * 4 + swz) * 8];
#pragma unroll
    for (int j = 0; j < 2; ++j)
      bfr[j] = *(const bf16x8*)&Bs[cur][((wn + j * 16 + fm) * 4 + swz) * 8];
#pragma unroll
    for (int i = 0; i < 4; ++i)
#pragma unroll
      for (int j = 0; j < 2; ++j)
        acc[i][j] = __builtin_amdgcn_mfma_f32_16x16x32_bf16(af[i], bfr[j], acc[i][j], 0, 0, 0);
    __syncthreads();   // one barrier/K-step: drains next-tile vmcnt + this tile's lgkm
    cur ^= 1;
  }

  const bool out_bf = (EPI == EPI_PRIOR) ? (*g.flag != 0) : false;
  const int em = (lane >> 4) * 4, en = lane & 15;
#pragma unroll
  for (int i = 0; i < 4; ++i) {
#pragma unroll
    for (int j = 0; j < 2; ++j) {
#pragma unroll
      for (int v = 0; v < 4; ++v) {
        int row = bm * 128 + wm + i * 16 + em + v;
        int col = bn * 64 + wn + j * 16 + en;
        float x = acc[i][j][v];
        if constexpr (EPI == EPI_ADD_BF16) {
          size_t o = (size_t)row * g.N + col;
          g.outh0[o] = f2bf(x + bf2f(g.addh[o]));
        } else if constexpr (EPI == EPI_XZ) {
          float val = x + g.bias[col];
          if (col < 1024) g.outh0[(size_t)row * 1024 + col] = f2bf(val);
          else            g.outh1[(size_t)row * 1024 + (col - 1024)] = f2bf(val);
        } else if constexpr (EPI == EPI_BIAS_F32) {
          g.outf0[(size_t)row * g.N + col] = x + g.bias[col];
        } else if constexpr (EPI == EPI_DTBC) {
          if (col < 1024) {
            float val = x + g.bias[col];
            float sp = (val > 20.f) ? val : log1pf(__expf(val));
            g.outf0[(size_t)row * 1024 + col] = sp;          // dt
          } else if (col < 1040) {
            g.outf1[(size_t)row * 16 + (col - 1024)] = x;     // Bp
          } else if (col < 1056) {
            g.outf2[(size_t)row * 16 + (col - 1040)] = x;     // Cp
          }
        } else {  // EPI_PRIOR: d_out[:, 1024:2048], dtype per flag
          float val = x + g.bias[col];
          size_t o = (size_t)row * 3072 + 1024 + col;
          if (out_bf) ((bf16_t*)g.outv)[o] = f2bf(val);
          else        ((float*)g.outv)[o]  = val;
        }
      }
    }
  }
}

// ---------------- chunked scan, phase 1 (xs is bf16 now) --------------------
__global__ __launch_bounds__(256) void scan_p1(const float* __restrict__ dt,
                                               const bf16_t* __restrict__ xsh,
                                               const float* __restrict__ Bp,
                                               const float* __restrict__ A_log,
                                               float* __restrict__ Gp,
                                               float* __restrict__ Hl) {
  int idx = blockIdx.x * 256 + threadIdx.x;
  int d = idx & 1023;
  int cb = idx >> 10;
  int b = cb & 7, c = cb >> 3;
  float Ad[16];
#pragma unroll
  for (int n = 0; n < 16; ++n) Ad[n] = -__expf(A_log[d * 16 + n]);
  float h[16] = {};
  float dts = 0.f;
  int r0 = c * CL_ * 8 + b;
  for (int tl = 0; tl < CL_; ++tl) {
    int r = r0 + tl * 8;
    size_t off = (size_t)r * 1024 + d;
    float dtv = dt[off], xv = bf2f(xsh[off]);
    float dtx = dtv * xv;
    dts += dtv;
    const float4* Bp4 = (const float4*)(Bp + r * 16);
    float4 b4[4] = {Bp4[0], Bp4[1], Bp4[2], Bp4[3]};
    const float* bv = (const float*)b4;
#pragma unroll
    for (int n = 0; n < 16; ++n) {
      float gg = __expf(dtv * Ad[n]);
      h[n] = gg * h[n] + dtx * bv[n];
    }
  }
  float* gp = Gp + (size_t)idx * 16;
  float* hl = Hl + (size_t)idx * 16;
#pragma unroll
  for (int q = 0; q < 4; ++q) {
    float4 gq, hq;
    gq.x = __expf(dts * Ad[q * 4 + 0]); gq.y = __expf(dts * Ad[q * 4 + 1]);
    gq.z = __expf(dts * Ad[q * 4 + 2]); gq.w = __expf(dts * Ad[q * 4 + 3]);
    hq.x = h[q * 4 + 0]; hq.y = h[q * 4 + 1]; hq.z = h[q * 4 + 2]; hq.w = h[q * 4 + 3];
    ((float4*)gp)[q] = gq;
    ((float4*)hl)[q] = hq;
  }
}

// ---------------- phase 2: inter-chunk carry scan; Cin overwrites Gp --------
__global__ __launch_bounds__(256) void scan_p2(float* __restrict__ GpCin,
                                               const float* __restrict__ Hl) {
  int j = blockIdx.x * 256 + threadIdx.x;
  float carry = 0.f;
#pragma unroll
  for (int c = 0; c < NC_; ++c) {
    size_t o = (size_t)c * 131072 + j;
    float gv = GpCin[o], hl = Hl[o];
    GpCin[o] = carry;
    carry = gv * carry + hl;
  }
}

// ---------------- phase 3: replay chunks from carry-in, emit gated y --------
__global__ __launch_bounds__(256) void scan_p3(const float* __restrict__ dt,
                                               const bf16_t* __restrict__ xsh,
                                               const bf16_t* __restrict__ xg,
                                               const float* __restrict__ Bp,
                                               const float* __restrict__ Cp,
                                               const float* __restrict__ A_log,
                                               const float* __restrict__ Dp,
                                               const float* __restrict__ Cin,
                                               float* __restrict__ y) {
  int idx = blockIdx.x * 256 + threadIdx.x;
  int d = idx & 1023;
  int cb = idx >> 10;
  int b = cb & 7, c = cb >> 3;
  float Ad[16];
#pragma unroll
  for (int n = 0; n < 16; ++n) Ad[n] = -__expf(A_log[d * 16 + n]);
  float Dd = Dp[d];
  float h[16];
  const float4* Ci4 = (const float4*)(Cin + (size_t)idx * 16);
#pragma unroll
  for (int q = 0; q < 4; ++q) {
    float4 cq = Ci4[q];
    h[q * 4 + 0] = cq.x; h[q * 4 + 1] = cq.y; h[q * 4 + 2] = cq.z; h[q * 4 + 3] = cq.w;
  }
  int r0 = c * CL_ * 8 + b;
  for (int tl = 0; tl < CL_; ++tl) {
    int r = r0 + tl * 8;
    size_t off = (size_t)r * 1024 + d;
    float dtv = dt[off], xv = bf2f(xsh[off]), gv = bf2f(xg[off]);
    float dtx = dtv * xv;
    const float4* Bp4 = (const float4*)(Bp + r * 16);
    const float4* Cp4 = (const float4*)(Cp + r * 16);
    float4 b4[4] = {Bp4[0], Bp4[1], Bp4[2], Bp4[3]};
    float4 c4[4] = {Cp4[0], Cp4[1], Cp4[2], Cp4[3]};
    const float* bv = (const float*)b4;
    const float* cv = (const float*)c4;
    float yv = 0.f;
#pragma unroll
    for (int n = 0; n < 16; ++n) {
      float gg = __expf(dtv * Ad[n]);
      h[n] = gg * h[n] + dtx * bv[n];
      yv += h[n] * cv[n];
    }
    yv += Dd * xv;
    float sg = gv / (1.f + __expf(-gv));   // silu(x_gate)
    y[off] = yv * sg;
  }
}

// ---------------- row LN; MODE 0: deter triple-write (+post_in assemble),
//                  MODE 1: +silu -> bf16 -------------------------------------
template <int MODE>
__global__ __launch_bounds__(256) void ln_k(const float* __restrict__ in,
                                            const float* __restrict__ gw,
                                            const float* __restrict__ bw,
                                            bf16_t* __restrict__ out0,
                                            void* __restrict__ out1,
                                            const bf16_t* __restrict__ embT,
                                            bf16_t* __restrict__ post_in,
                                            const int* __restrict__ flag) {
  const bool out_bf = (MODE == 0) ? (*flag != 0) : false;
  int r = blockIdx.x, tid = threadIdx.x;
  float v[4];
  float s = 0.f, ss = 0.f;
#pragma unroll
  for (int i = 0; i < 4; ++i) {
    v[i] = in[(size_t)r * 1024 + i * 256 + tid];
    s += v[i]; ss += v[i] * v[i];
  }
  block_sum2(s, ss);   // barrier: all row reads resolved before any write below
  float mean = s * (1.f / 1024.f);
  float var  = ss * (1.f / 1024.f) - mean * mean;
  float rstd = rsqrtf(var + 1e-5f);
#pragma unroll
  for (int i = 0; i < 4; ++i) {
    int c = i * 256 + tid;
    float yv = (v[i] - mean) * rstd * gw[c] + bw[c];
    if constexpr (MODE == 1) yv = yv / (1.f + __expf(-yv));
    out0[(size_t)r * 1024 + c] = f2bf(yv);
    if constexpr (MODE == 0) {
      size_t o = (size_t)r * 3072 + c;
      if (out_bf) ((bf16_t*)out1)[o] = f2bf(yv);
      else        ((float*)out1)[o]  = yv;
      post_in[(size_t)r * 2048 + c] = f2bf(yv);
      post_in[(size_t)r * 2048 + 1024 + c] = embT[(size_t)r * 1024 + c];
    }
  }
}

// ---------------- softmax over 32 classes + unimix + log -------------------
__global__ __launch_bounds__(256) void softmax_k(const float* __restrict__ logits,
                                                 void* __restrict__ out,
                                                 const int* __restrict__ flag) {
  const bool out_bf = (*flag != 0);
  int idx = blockIdx.x * 256 + threadIdx.x;
  int r = idx >> 5, grp = idx & 31;
  const float* p = logits + (size_t)r * 1024 + grp * 32;
  float x[32];
  float m = -1e30f;
#pragma unroll
  for (int j = 0; j < 32; ++j) { x[j] = p[j]; m = fmaxf(m, x[j]); }
  float sum = 0.f;
#pragma unroll
  for (int j = 0; j < 32; ++j) { x[j] = __expf(x[j] - m); sum += x[j]; }
  float inv = 0.99f / sum;
  size_t base = (size_t)r * 3072 + 2048 + grp * 32;
#pragma unroll
  for (int j = 0; j < 32; ++j) {
    float val = logf(x[j] * inv + (0.01f / 32.f) + 1e-8f);
    if (out_bf) ((bf16_t*)out)[base + j] = f2bf(val);
    else        ((float*)out)[base + j]  = val;
  }
}

// ===========================================================================
extern "C" void kernel_launch(void* const* d_in, const int* in_sizes, int n_in,
                              void* d_out, int out_size, void* d_ws, size_t ws_size,
                              hipStream_t stream) {
  (void)in_sizes; (void)n_in; (void)out_size; (void)ws_size;
  const void* actions = d_in[0];
  const void* embeds  = d_in[1];
  const void* W_pre   = d_in[2];
  const void* b_pre   = d_in[3];
  const void* g_pre   = d_in[4];
  const void* bb_pre  = d_in[5];
  const void* W_emb   = d_in[6];
  const void* W_in    = d_in[7];
  const void* b_in    = d_in[8];
  const void* W_dt    = d_in[9];
  const void* b_dt    = d_in[10];
  const void* W_B     = d_in[11];
  const void* W_C     = d_in[12];
  const void* A_log   = d_in[13];
  const void* Dp      = d_in[14];
  const void* g_out   = d_in[15];
  const void* b_out   = d_in[16];
  const void* W_pr1   = d_in[17];
  const void* b_pr1   = d_in[18];
  const void* g_pr    = d_in[19];
  const void* bb_pr   = d_in[20];
  const void* W_pr2   = d_in[21];
  const void* b_pr2   = d_in[22];
  const void* W_po1   = d_in[23];
  const void* b_po1   = d_in[24];
  const void* g_po    = d_in[25];
  const void* bb_po   = d_in[26];
  const void* W_po2   = d_in[27];
  const void* b_po2   = d_in[28];

  // ---- workspace layout (offsets in KB; ~99.2 MB total). Aliases:
  //   Hl @ F5; Gp @ F2 (free until z2); B9 (x_ssm bf16) stays LIVE thru scan.
  char* ws = (char*)d_ws;
  const size_t KB = 1024;
  bf16_t* WTemb  = (bf16_t*)(ws + 0 * KB);       // 1024x1024 (2 MB)
  bf16_t* WTin   = (bf16_t*)(ws + 2048 * KB);    // 2048x1024 (4 MB)
  bf16_t* WTdtbc = (bf16_t*)(ws + 6144 * KB);    // 1088x1024 (2.125 MB)
  bf16_t* WTpr1  = (bf16_t*)(ws + 8320 * KB);
  bf16_t* WTpr2  = (bf16_t*)(ws + 10368 * KB);
  bf16_t* WTpo1  = (bf16_t*)(ws + 12416 * KB);   // 1024x2048 (4 MB)
  bf16_t* WTpo2  = (bf16_t*)(ws + 16512 * KB);
  bf16_t* embT   = (bf16_t*)(ws + 18560 * KB);   // 4096x1024 bf16 (8 MB)
  float*  F1     = (float*)(ws + 26752 * KB);    // pre_raw -> dt -> z1 -> logits
  float*  F2     = (float*)(ws + 43136 * KB);    // (Gp during scan) -> z2
  float*  F5     = (float*)(ws + 59520 * KB);    // (Hl) -> y -> post_in(bf16)
  bf16_t* B8     = (bf16_t*)(ws + 75904 * KB);   // act_h -> x -> h1 -> h2
  bf16_t* B9     = (bf16_t*)(ws + 84096 * KB);   // x_ssm bf16 (live thru scan) -> deter
  bf16_t* G8     = (bf16_t*)(ws + 92288 * KB);   // x_gate bf16
  float*  BpB    = (float*)(ws + 100480 * KB);   // 4096x16
  float*  CpB    = (float*)(ws + 100736 * KB);
  float*  Hl     = (float*)(ws + 59520 * KB);    // 16 MB (aliases F5)
  float*  Gp     = (float*)(ws + 43136 * KB);    // 16 MB (aliases F2)
  char* cb = ws + 100992 * KB;
  int*   flag    = (int*)(cb);                cb += 256;
  float* Alog_f  = (float*)(cb);              cb += 16384 * 4;
  float* Dp_f    = (float*)(cb);              cb += 1024 * 4;
  float* bpre_f  = (float*)(cb);              cb += 1024 * 4;
  float* gpre_f  = (float*)(cb);              cb += 1024 * 4;
  float* bbpre_f = (float*)(cb);              cb += 1024 * 4;
  float* bin_f   = (float*)(cb);              cb += 2048 * 4;
  float* bdt_f   = (float*)(cb);              cb += 1024 * 4;
  float* gout_f  = (float*)(cb);              cb += 1024 * 4;
  float* bout_f  = (float*)(cb);              cb += 1024 * 4;
  float* bpr1_f  = (float*)(cb);              cb += 1024 * 4;
  float* gpr_f   = (float*)(cb);              cb += 1024 * 4;
  float* bbpr_f  = (float*)(cb);              cb += 1024 * 4;
  float* bpr2_f  = (float*)(cb);              cb += 1024 * 4;
  float* bpo1_f  = (float*)(cb);              cb += 1024 * 4;
  float* gpo_f   = (float*)(cb);              cb += 1024 * 4;
  float* bbpo_f  = (float*)(cb);              cb += 1024 * 4;
  float* bpo2_f  = (float*)(cb);              cb += 1024 * 4;
  bf16_t* actA   = (bf16_t*)(cb);             cb += 4096 * 32 * 2;    // 256 KB
  bf16_t* WTpre  = (bf16_t*)(cb);             cb += 1024 * 32 * 2;    // 64 KB

  detect_k<<<1, 64, 0, stream>>>((const unsigned int*)Dp, flag);

  CvtArgs ca{};
  const void* srcs[17] = {A_log, Dp, b_pre, g_pre, bb_pre, b_in, b_dt,
                          g_out, b_out, b_pr1, g_pr, bb_pr, b_pr2,
                          b_po1, g_po, bb_po, b_po2};
  float* dsts[17] = {Alog_f, Dp_f, bpre_f, gpre_f, bbpre_f, bin_f, bdt_f,
                     gout_f, bout_f, bpr1_f, gpr_f, bbpr_f, bpr2_f,
                     bpo1_f, gpo_f, bbpo_f, bpo2_f};
  int ns[17] = {16384, 1024, 1024, 1024, 1024, 2048, 1024,
                1024, 1024, 1024, 1024, 1024, 1024,
                1024, 1024, 1024, 1024};
  for (int i = 0; i < 17; ++i) { ca.src[i] = srcs[i]; ca.dst[i] = dsts[i]; ca.n[i] = ns[i]; }
  cvt_vecs<<<dim3(8, 17), 256, 0, stream>>>(ca, flag);

  {  // all 8 weight transposes in one dispatch; W_dt^T lands in WTdtbc rows 0-1023
    TrArgs ta{};
    const void* tsrc[8] = {W_emb, W_in, W_dt, W_pr1, W_pr2, W_po1, W_po2, W_pre};
    bf16_t* tdst[8] = {WTemb, WTin, WTdtbc, WTpr1, WTpr2, WTpo1, WTpo2, WTpre};
    int tK[8] = {1024, 1024, 1024, 1024, 1024, 2048, 1024, 32};
    int tN[8] = {1024, 2048, 1024, 1024, 1024, 1024, 1024, 1024};
    int off = 0;
    for (int i = 0; i < 8; ++i) {
      ta.src[i] = tsrc[i]; ta.dst[i] = tdst[i]; ta.K[i] = tK[i]; ta.N[i] = tN[i];
      ta.tile0[i] = off; off += (tK[i] >> 5) * (tN[i] >> 5);
    }
    ta.tile0[8] = off;
    tr_batch<<<off, dim3(32, 8), 0, stream>>>(ta, flag);
  }
  bc_build<<<256, 256, 0, stream>>>(W_B, W_C, WTdtbc, flag);

  reorder_emb<<<R_, 256, 0, stream>>>(embeds, embT, flag);
  reorder_act<<<512, 256, 0, stream>>>(actions, actA, flag);

  {  // pre_raw = actions @ W_pre + b_pre -> f32 (F5); K=32 single MFMA step
    GemmArgs a{}; a.A = actA; a.Bt = WTpre; a.K = 32; a.N = 1024; a.bnN = 16;
    a.bias = bpre_f; a.outf0 = F5;
    gemm_t<EPI_BIAS_F32><<<512, 256, 0, stream>>>(a);
  }
  // act_h = silu(LN(pre_raw)) -> bf16 (B8)
  ln_k<1><<<R_, 256, 0, stream>>>(F5, gpre_f, bbpre_f, B8, nullptr,
                                  nullptr, nullptr, flag);
  {  // x = embT @ W_emb + act_h -> bf16 (G8); addend B8 read-only here
    GemmArgs a{}; a.A = embT; a.Bt = WTemb; a.K = 1024; a.N = 1024; a.bnN = 16;
    a.addh = B8; a.outh0 = G8;
    gemm_t<EPI_ADD_BF16><<<512, 256, 0, stream>>>(a);
  }
  {  // xz = x @ W_in + b_in -> x_ssm (bf16 B9), x_gate (bf16 B8)
    GemmArgs a{}; a.A = G8; a.Bt = WTin; a.K = 1024; a.N = 2048; a.bnN = 32;
    a.bias = bin_f; a.outh0 = B9; a.outh1 = B8;
    gemm_t<EPI_XZ><<<1024, 256, 0, stream>>>(a);
  }
  {  // dt=softplus(x_ssm@W_dt+b_dt)->F1; Bp/Cp = x_ssm@[W_B|W_C] (fused)
     // N=1088 = 17 x 64 exactly; all Bt rows valid (rows 1056-1087 zeros).
    GemmArgs a{}; a.A = B9; a.Bt = WTdtbc; a.K = 1024; a.N = 1088; a.bnN = 17;
    a.bias = bdt_f; a.outf0 = F1; a.outf1 = BpB; a.outf2 = CpB;
    gemm_t<EPI_DTBC><<<544, 256, 0, stream>>>(a);
  }
  // chunked selective scan: 32 chunks x 16 steps (xs = B9 bf16, xg = B8)
  scan_p1<<<1024, 256, 0, stream>>>(F1, B9, BpB, Alog_f, Gp, Hl);
  scan_p2<<<512, 256, 0, stream>>>(Gp, Hl);
  scan_p3<<<1024, 256, 0, stream>>>(F1, B9, B8, BpB, CpB, Alog_f, Dp_f, Gp, F5);
  // deter = LN(y) -> bf16 (B9), d_out[:, 0:1024], and fused post_in (F5)
  ln_k<0><<<R_, 256, 0, stream>>>(F5, gout_f, bout_f, B9, d_out,
                                  embT, (bf16_t*)F5, flag);
  {  // z1 = deter @ W_pr1 + b_pr1 -> f32 (F1)
    GemmArgs a{}; a.A = B9; a.Bt = WTpr1; a.K = 1024; a.N = 1024; a.bnN = 16;
    a.bias = bpr1_f; a.outf0 = F1;
    gemm_t<EPI_BIAS_F32><<<512, 256, 0, stream>>>(a);
  }
  ln_k<1><<<R_, 256, 0, stream>>>(F1, gpr_f, bbpr_f, B8, nullptr,
                                  nullptr, nullptr, flag);  // h1
  {  // prior = h1 @ W_pr2 + b_pr2 -> d_out[:, 1024:2048]
    GemmArgs a{}; a.A = B8; a.Bt = WTpr2; a.K = 1024; a.N = 1024; a.bnN = 16;
    a.bias = bpr2_f; a.outv = d_out; a.flag = flag;
    gemm_t<EPI_PRIOR><<<512, 256, 0, stream>>>(a);
  }
  {  // z2 = post_in @ W_po1 + b_po1 -> f32 (F2)
    GemmArgs a{}; a.A = (bf16_t*)F5; a.Bt = WTpo1; a.K = 2048; a.N = 1024; a.bnN = 16;
    a.bias = bpo1_f; a.outf0 = F2;
    gemm_t<EPI_BIAS_F32><<<512, 256, 0, stream>>>(a);
  }
  ln_k<1><<<R_, 256, 0, stream>>>(F2, gpo_f, bbpo_f, B8, nullptr,
                                  nullptr, nullptr, flag);  // h2
  {  // logits = h2 @ W_po2 + b_po2 -> f32 (F1)
    GemmArgs a{}; a.A = B8; a.Bt = WTpo2; a.K = 1024; a.N = 1024; a.bnN = 16;
    a.bias = bpo2_f; a.outf0 = F1;
    gemm_t<EPI_BIAS_F32><<<512, 256, 0, stream>>>(a);
  }
  softmax_k<<<512, 256, 0, stream>>>(F1, d_out, flag);
}